// Round 9
// baseline (178.036 us; speedup 1.0000x reference)
//
#include <hip/hip_runtime.h>
#include <hip/hip_bf16.h>

typedef __attribute__((ext_vector_type(4))) float f32x4;
typedef __attribute__((ext_vector_type(2))) long longx2;   // 16 B load

#define N_ROWS 8192
#define B_HALF 4096
#define EXP2C 2.885390081777927f   // 2*log2(e): exp(2S) = exp2(S*EXP2C)

// ws layout (bytes)
#define WS_ZN       0                    // fp8 frag-major [512 groups][4096 B] = 2 MB
#define WS_ROWACC   2097152              // float[8192]  sum_j exp(2 S_ij)
#define WS_POS      2129920              // float[8192]  raw S_pos
#define WS_DIAG     2162688              // float[8192]  exp2(S_ii*EXP2C)
#define WS_ACC      2195456              // float final accum
#define WS_CNT      2195460              // uint  block counter

__device__ __forceinline__ float fexp2(float x) {
#if __has_builtin(__builtin_amdgcn_exp2f)
    return __builtin_amdgcn_exp2f(x);
#else
    return exp2f(x);
#endif
}

__device__ __forceinline__ void async_copy16(const void* g, void* l) {
    __builtin_amdgcn_global_load_lds(
        (const __attribute__((address_space(1))) unsigned int*)g,
        (__attribute__((address_space(3))) unsigned int*)l,
        16, 0, 0);
}

// ---------------- Phase 1: normalize -> fp8, FRAGMENT-MAJOR layout -----------
// (validated R6-R8, absmax 0.0)
// element k of row r stored at:
//   (r>>4)*4096 + (k>>6)*1024 + (r&15)*64 + ((k>>3)&3)*16 + ((k>>5)&1)*8 + (k&7)
__global__ __launch_bounds__(256) void normalize_k(
    const float* __restrict__ z_orig, const float* __restrict__ z_aug,
    unsigned char* __restrict__ zn, float* __restrict__ rowAcc,
    float* __restrict__ accum, unsigned int* __restrict__ cnt)
{
    if (blockIdx.x == 0 && threadIdx.x == 0) { *accum = 0.0f; *cnt = 0u; }
    const int row  = blockIdx.x * 4 + (threadIdx.x >> 6);
    const int lane = threadIdx.x & 63;
    if (lane == 0) rowAcc[row] = 0.0f;       // zeroed before tile_k (stream order)
    const float* src = (row < B_HALF) ? (z_aug  + (size_t)row * 256)
                                      : (z_orig + (size_t)(row - B_HALF) * 256);
    float4 v = ((const float4*)src)[lane];
    float ss = v.x*v.x + v.y*v.y + v.z*v.z + v.w*v.w;
    #pragma unroll
    for (int m = 1; m < 64; m <<= 1) ss += __shfl_xor(ss, m);
    float inv = 1.0f / fmaxf(sqrtf(ss), 1e-8f);
    int pk = 0;
    pk = __builtin_amdgcn_cvt_pk_fp8_f32(v.x * inv, v.y * inv, pk, false);
    pk = __builtin_amdgcn_cvt_pk_fp8_f32(v.z * inv, v.w * inv, pk, true);
    const int addr = ((row >> 4) << 12) | ((lane >> 4) << 10) | ((row & 15) << 6)
                   | (((lane >> 1) & 3) << 4) | (((lane >> 3) & 1) << 3)
                   | ((lane & 1) << 2);
    *(int*)(zn + addr) = pk;
}

// ---------------- Phase 2: A-strip-resident tile blocks (spill-proofed) ------
// Block (rb, cx): A-strip rb (32 KB, bank-swizzled) staged to LDS once; up to
// 2 tiles cb = rb+2*cx, +1 processed back-to-back. Wave w owns cols
// [cb*128+w*32, +32) x 128 rows (acc[8][2] in AGPR). B frags: bc[2] per t4
// with one-step prefetch bn[2]; A frags in chunks of 4. Live regs ~111 < 128
// so the allocator can hit 4 waves/SIMD without scratch.
__global__ __launch_bounds__(256) __attribute__((amdgpu_waves_per_eu(2, 4)))
void tile_k(
    const unsigned char* __restrict__ zn,
    float* __restrict__ rowAcc,         // [8192] += sum_j exp(2 S_ij)
    float* __restrict__ posv,           // [8192] raw S_pos
    float* __restrict__ diagE)          // [8192] exp2(S_ii*EXP2C)
{
    __shared__ unsigned char As[32768];

    const int rb  = blockIdx.y;
    const int cb0 = rb + blockIdx.x * 2;
    if (cb0 > 63) return;                    // block-uniform, before any barrier
    const int nt = min(2, 64 - cb0);

    const int t      = threadIdx.x;
    const int lane   = t & 63;
    const int w      = t >> 6;
    const int lane15 = lane & 15;
    const int quad   = lane >> 4;
    const int rowBase = rb * 128;

    // ---- stage A strip, swizzled (validated R8: 0 bank conflicts) ----
    // dest granule (t4, r15, p) sources logical quad q = (p - (r15>>1)) & 3
    {
        const unsigned char* gA = zn + (size_t)rb * 32768;
        const int r15 = (t >> 2) & 15;
        const int q   = ((t & 3) - (r15 >> 1)) & 3;
        const int dstOff = t * 16;
        const int srcOff = (dstOff & ~63) | (q << 4);
        #pragma unroll
        for (int s = 0; s < 8; ++s)
            async_copy16(gA + s * 4096 + srcOff, As + s * 4096 + dstOff);
    }
    __syncthreads();                         // the only barrier

    const int aOff = lane15 * 64 + (((quad + (lane15 >> 1)) & 3) << 4); // swizzled
    const int gOff = lane15 * 64 + quad * 16;                            // logical
    const bool diagLane = (lane15 >> 2) == quad;
    const int  rsel = lane15 & 3;

    #pragma unroll 1
    for (int ti = 0; ti < nt; ++ti) {
        const int cb = cb0 + ti;
        const bool isDiag = (cb == rb);
        const unsigned char* gB = zn + (size_t)(cb * 8 + 2 * w) * 4096 + gOff;
        const unsigned char* lB = As + (2 * w) * 4096 + aOff;

        f32x4 acc[8][2];
        #pragma unroll
        for (int mi = 0; mi < 8; ++mi)
            #pragma unroll
            for (int nj = 0; nj < 2; ++nj)
                acc[mi][nj] = (f32x4){0.f, 0.f, 0.f, 0.f};

        longx2 bc[2], bn[2];
        #pragma unroll
        for (int nj = 0; nj < 2; ++nj)
            bc[nj] = isDiag ? *(const longx2*)(lB + nj * 4096)
                            : *(const longx2*)(gB + nj * 4096);

        #pragma unroll 1
        for (int t4 = 0; t4 < 4; ++t4) {
            if (t4 < 3) {                    // one-step B prefetch
                const int o = (t4 + 1) * 1024;
                #pragma unroll
                for (int nj = 0; nj < 2; ++nj)
                    bn[nj] = isDiag ? *(const longx2*)(lB + nj * 4096 + o)
                                    : *(const longx2*)(gB + nj * 4096 + o);
            }
            #pragma unroll
            for (int mh = 0; mh < 2; ++mh) {
                longx2 af[4];
                #pragma unroll
                for (int m2 = 0; m2 < 4; ++m2)
                    af[m2] = *(const longx2*)(As + (mh * 4 + m2) * 4096
                                              + t4 * 1024 + aOff);
                #pragma unroll
                for (int m2 = 0; m2 < 4; ++m2)
                    #pragma unroll
                    for (int nj = 0; nj < 2; ++nj)
                        acc[mh * 4 + m2][nj] = __builtin_amdgcn_mfma_f32_16x16x32_fp8_fp8(
                            af[m2].x, bc[nj].x, acc[mh * 4 + m2][nj], 0, 0, 0);
                #pragma unroll
                for (int m2 = 0; m2 < 4; ++m2)
                    #pragma unroll
                    for (int nj = 0; nj < 2; ++nj)
                        acc[mh * 4 + m2][nj] = __builtin_amdgcn_mfma_f32_16x16x32_fp8_fp8(
                            af[m2].y, bc[nj].y, acc[mh * 4 + m2][nj], 0, 0, 0);
            }
            bc[0] = bn[0]; bc[1] = bn[1];
        }

        // ---- epilogue (validated R7/R8, absmax 0.0) ----
        // frag (mi,nj): row = rowBase + mi*16 + quad*4 + r,
        //               col = cb*128 + w*32 + nj*16 + lane15
        if (isDiag && diagLane) {
            #pragma unroll
            for (int nj = 0; nj < 2; ++nj) {
                const int mi = 2 * w + nj;
                diagE[rowBase + mi * 16 + lane15] = fexp2(acc[mi][nj][rsel] * EXP2C);
            }
        }
        if (cb == rb + 32 && diagLane) {      // positive-pair diagonal
            #pragma unroll
            for (int nj = 0; nj < 2; ++nj) {
                const int mi = 2 * w + nj;
                float v = acc[mi][nj][rsel];
                posv[rowBase + mi * 16 + lane15] = v;
                posv[rowBase + mi * 16 + lane15 + B_HALF] = v;
            }
        }

        #pragma unroll
        for (int mi = 0; mi < 8; ++mi)
            #pragma unroll
            for (int nj = 0; nj < 2; ++nj)
                #pragma unroll
                for (int r = 0; r < 4; ++r)
                    acc[mi][nj][r] = fexp2(acc[mi][nj][r] * EXP2C);

        // row sums over this wave's 32 cols
        #pragma unroll
        for (int mi = 0; mi < 8; ++mi)
            #pragma unroll
            for (int r = 0; r < 4; ++r) {
                float s = acc[mi][0][r] + acc[mi][1][r];
                s += __shfl_xor(s, 1);
                s += __shfl_xor(s, 2);
                s += __shfl_xor(s, 4);
                s += __shfl_xor(s, 8);
                if (lane15 == 0)
                    atomicAdd(&rowAcc[rowBase + mi * 16 + quad * 4 + r], s);
            }

        // col sums over all 128 rows (off-diagonal tiles only)
        if (!isDiag) {
            #pragma unroll
            for (int nj = 0; nj < 2; ++nj) {
                float s = 0.0f;
                #pragma unroll
                for (int mi = 0; mi < 8; ++mi)
                    s += acc[mi][nj][0] + acc[mi][nj][1]
                       + acc[mi][nj][2] + acc[mi][nj][3];
                s += __shfl_xor(s, 16);
                s += __shfl_xor(s, 32);
                if (quad == 0)
                    atomicAdd(&rowAcc[cb * 128 + w * 32 + nj * 16 + lane15], s);
            }
        }
    }
}

// ---------------- Phase 3: per-row loss + grid reduction (last block) --------
__global__ __launch_bounds__(256) void loss_k(
    const float* __restrict__ rowAcc, const float* __restrict__ posv,
    const float* __restrict__ diagE, float* __restrict__ accum,
    unsigned int* __restrict__ cnt, float* __restrict__ out)
{
    const int i = blockIdx.x * 256 + threadIdx.x;
    float s = rowAcc[i] - diagE[i];             // drop main-diagonal term
    float loss = __logf(s) - 2.0f * posv[i];    // logits = 2*S (tau = 0.5)

    #pragma unroll
    for (int m = 1; m < 64; m <<= 1) loss += __shfl_xor(loss, m);
    __shared__ float red[4];
    if ((threadIdx.x & 63) == 0) red[threadIdx.x >> 6] = loss;
    __syncthreads();
    if (threadIdx.x == 0) {
        float bs = red[0] + red[1] + red[2] + red[3];
        atomicAdd(accum, bs);
        __threadfence();
        unsigned int old = atomicAdd(cnt, 1u);
        if (old == 31u) {                       // last of 32 blocks
            __threadfence();
            float total = atomicAdd(accum, 0.0f);
            out[0] = total * (1.0f / (float)N_ROWS);
        }
    }
}

extern "C" void kernel_launch(void* const* d_in, const int* in_sizes, int n_in,
                              void* d_out, int out_size, void* d_ws, size_t ws_size,
                              hipStream_t stream) {
    const float* z_orig = (const float*)d_in[0];
    const float* z_aug  = (const float*)d_in[1];
    char* ws = (char*)d_ws;
    unsigned char* zn   = (unsigned char*)(ws + WS_ZN);
    float* rowAcc       = (float*)(ws + WS_ROWACC);
    float* posv         = (float*)(ws + WS_POS);
    float* diagE        = (float*)(ws + WS_DIAG);
    float* accum        = (float*)(ws + WS_ACC);
    unsigned int* cnt   = (unsigned int*)(ws + WS_CNT);

    normalize_k<<<N_ROWS / 4, 256, 0, stream>>>(z_orig, z_aug, zn, rowAcc, accum, cnt);
    tile_k<<<dim3(32, 64), 256, 0, stream>>>(zn, rowAcc, posv, diagE);
    loss_k<<<N_ROWS / 256, 256, 0, stream>>>(rowAcc, posv, diagE, accum, cnt,
                                             (float*)d_out);
}

// Round 10
// 96.153 us; speedup vs baseline: 1.8516x; 1.8516x over previous
//
#include <hip/hip_runtime.h>
#include <hip/hip_bf16.h>

typedef __attribute__((ext_vector_type(4))) float f32x4;
typedef __attribute__((ext_vector_type(4))) int   i32x4;
typedef __attribute__((ext_vector_type(8))) int   i32x8;

#define N_ROWS 8192
#define B_HALF 4096
#define NUT   2080          // 64*65/2 upper-triangle 128x128 tiles
// exp(2S) where acc = 256*S (inputs pre-scaled x16): exp2(acc * 2*log2e/256)
#define EXP2C4 0.01127105500694503f
#define SCL1   0x7F7F7F7Fu  // E8M0 127 in all bytes -> scale 1.0

// ws layout (bytes)
#define WS_ZN       0                    // fp4 frag-major [512 groups][2048 B] = 1 MB
#define WS_ROWACC   2097152              // float[8192]  sum_j exp(2 S_ij)
#define WS_POS      2129920              // float[8192]  raw acc_pos (= 256*S_pos)
#define WS_DIAG     2162688              // float[8192]  exp2(acc_ii*EXP2C4)
#define WS_ACC      2195456              // float final accum
#define WS_CNT      2195460              // uint  block counter

__device__ __forceinline__ float fexp2(float x) {
#if __has_builtin(__builtin_amdgcn_exp2f)
    return __builtin_amdgcn_exp2f(x);
#else
    return exp2f(x);
#endif
}

// round-to-nearest e2m1 code (values 0,.5,1,1.5,2,3,4,6), sign in bit 3
__device__ __forceinline__ unsigned int q4(float x) {
    float a = fabsf(x);
    unsigned int s = (__float_as_uint(x) >> 31) << 3;
    unsigned int c = a < 0.25f ? 0u : a < 0.75f ? 1u : a < 1.25f ? 2u
                   : a < 1.75f ? 3u : a < 2.5f  ? 4u : a < 3.5f  ? 5u
                   : a < 5.0f  ? 6u : 7u;
    return c | s;
}

__device__ __forceinline__ i32x8 widen(i32x4 v) {
    return (i32x8){v.x, v.y, v.z, v.w, 0, 0, 0, 0};
}

// ---------------- Phase 1: normalize -> fp4 (x16), FRAGMENT-MAJOR ------------
// element k of row r (16B granule = 32 elems, nibbles ascending k, low first):
//   addr = (r>>4)*2048 + (k>>7)*1024 + (r&15)*64 + ((k>>5)&3)*16 + ((k&31)>>1)
__global__ __launch_bounds__(256) void normalize_k(
    const float* __restrict__ z_orig, const float* __restrict__ z_aug,
    unsigned char* __restrict__ zn, float* __restrict__ rowAcc,
    float* __restrict__ accum, unsigned int* __restrict__ cnt)
{
    if (blockIdx.x == 0 && threadIdx.x == 0) { *accum = 0.0f; *cnt = 0u; }
    const int row  = blockIdx.x * 4 + (threadIdx.x >> 6);
    const int lane = threadIdx.x & 63;
    if (lane == 0) rowAcc[row] = 0.0f;       // zeroed before tile_k (stream order)
    const float* src = (row < B_HALF) ? (z_aug  + (size_t)row * 256)
                                      : (z_orig + (size_t)(row - B_HALF) * 256);
    float4 v = ((const float4*)src)[lane];
    float ss = v.x*v.x + v.y*v.y + v.z*v.z + v.w*v.w;
    #pragma unroll
    for (int m = 1; m < 64; m <<= 1) ss += __shfl_xor(ss, m);
    float inv = 16.0f / fmaxf(sqrtf(ss), 1e-8f);   // x16 pre-scale into e2m1 range
    unsigned int pk = q4(v.x * inv) | (q4(v.y * inv) << 4)
                    | (q4(v.z * inv) << 8) | (q4(v.w * inv) << 12);
    // lane covers k = 4*lane..4*lane+3: ks = lane>>5, q = (lane>>3)&3
    const int addr = ((row >> 4) << 11) | ((lane >> 5) << 10) | ((row & 15) << 6)
                   | (((lane >> 3) & 3) << 4) | ((lane & 7) << 1);
    *(unsigned short*)(zn + addr) = (unsigned short)pk;
}

// ---------------- Phase 2: LDS-free fp4 128x128 tiles ------------------------
// R6's proven structure (no LDS, no barriers, 2080 independent blocks), fp4
// operands: 16 coalesced dwordx4 loads + 32 scale-MFMAs (K=128) per wave.
__global__ __launch_bounds__(256, 3) void tile_k(
    const unsigned char* __restrict__ zn,
    float* __restrict__ rowAcc,         // [8192] += sum_j exp(2 S_ij)
    float* __restrict__ posv,           // [8192] raw acc_pos
    float* __restrict__ diagE)          // [8192] exp2(acc_ii*EXP2C4)
{
    const int bid = blockIdx.x;
    // decode upper-triangular (rb, cb), cb >= rb; C(r) = r*(129-r)/2
    int rb = (int)((129.0f - sqrtf(16641.0f - 8.0f * (float)bid)) * 0.5f);
    rb = rb < 0 ? 0 : (rb > 63 ? 63 : rb);
    while ((rb + 1) * (129 - (rb + 1)) / 2 <= bid) ++rb;
    while (rb * (129 - rb) / 2 > bid) --rb;
    const int cb = rb + (bid - rb * (129 - rb) / 2);

    const int t      = threadIdx.x;
    const int lane   = t & 63;
    const int w      = t >> 6;
    const int wy     = w >> 1;
    const int wx     = w & 1;
    const int lane15 = lane & 15;
    const int quad   = lane >> 4;
    const int rowBase = rb * 128;
    const int colBase = cb * 128;

    // wave's fragment pointers (1 KB coalesced per load instruction)
    const int laneOff = lane15 * 64 + quad * 16;
    const unsigned char* gA = zn + (size_t)(rb * 8 + wy * 4) * 2048 + laneOff;
    const unsigned char* gB = zn + (size_t)(cb * 8 + wx * 4) * 2048 + laneOff;

    f32x4 acc[4][4];
    #pragma unroll
    for (int i = 0; i < 4; ++i)
        #pragma unroll
        for (int j = 0; j < 4; ++j)
            acc[i][j] = (f32x4){0.f, 0.f, 0.f, 0.f};

    #pragma unroll 1
    for (int ks = 0; ks < 2; ++ks) {
        i32x4 a[4], b[4];
        #pragma unroll
        for (int mi = 0; mi < 4; ++mi)
            a[mi] = *(const i32x4*)(gA + mi * 2048 + ks * 1024);
        #pragma unroll
        for (int ni = 0; ni < 4; ++ni)
            b[ni] = *(const i32x4*)(gB + ni * 2048 + ks * 1024);
        #pragma unroll
        for (int mi = 0; mi < 4; ++mi)
            #pragma unroll
            for (int ni = 0; ni < 4; ++ni)
                acc[mi][ni] = __builtin_amdgcn_mfma_scale_f32_16x16x128_f8f6f4(
                    widen(a[mi]), widen(b[ni]), acc[mi][ni],
                    4, 4,                     // cbsz=4 (fp4 A), blgp=4 (fp4 B)
                    0, SCL1, 0, SCL1);        // opsel/scale: all-ones scales
    }

    // C/D layout: m-row = quad*4 + reg, n-col = lane15 (validated r1-r9;
    // shape-determined, dtype-independent).
    const bool diagLane = (wy == wx) && ((lane15 >> 2) == quad);
    const int  rsel = lane15 & 3;
    if (cb == rb && diagLane) {
        #pragma unroll
        for (int mi = 0; mi < 4; ++mi) {
            int grow = rowBase + wy * 64 + mi * 16 + lane15;
            diagE[grow] = fexp2(acc[mi][mi][rsel] * EXP2C4);
        }
    }
    if (cb == rb + 32 && diagLane) {         // positive-pair diagonal
        #pragma unroll
        for (int mi = 0; mi < 4; ++mi) {
            int grow = rowBase + wy * 64 + mi * 16 + lane15;
            float v = acc[mi][mi][rsel];
            posv[grow] = v;
            posv[grow + B_HALF] = v;
        }
    }

    // exp(2*S) in place (acc = 256*S)
    #pragma unroll
    for (int mi = 0; mi < 4; ++mi)
        #pragma unroll
        for (int ni = 0; ni < 4; ++ni)
            #pragma unroll
            for (int r = 0; r < 4; ++r)
                acc[mi][ni][r] = fexp2(acc[mi][ni][r] * EXP2C4);

    // row sums (over n): global atomics, no barrier
    #pragma unroll
    for (int mi = 0; mi < 4; ++mi)
        #pragma unroll
        for (int r = 0; r < 4; ++r) {
            float s = acc[mi][0][r] + acc[mi][1][r] + acc[mi][2][r] + acc[mi][3][r];
            s += __shfl_xor(s, 1);
            s += __shfl_xor(s, 2);
            s += __shfl_xor(s, 4);
            s += __shfl_xor(s, 8);
            if (lane15 == 0)
                atomicAdd(&rowAcc[rowBase + wy * 64 + mi * 16 + quad * 4 + r], s);
        }

    // col sums (over m); off-diagonal tiles only
    if (cb != rb) {
        #pragma unroll
        for (int ni = 0; ni < 4; ++ni) {
            float s = 0.0f;
            #pragma unroll
            for (int mi = 0; mi < 4; ++mi)
                s += acc[mi][ni][0] + acc[mi][ni][1] + acc[mi][ni][2] + acc[mi][ni][3];
            s += __shfl_xor(s, 16);
            s += __shfl_xor(s, 32);
            if (quad == 0)
                atomicAdd(&rowAcc[colBase + wx * 64 + ni * 16 + lane15], s);
        }
    }
}

// ---------------- Phase 3: per-row loss + grid reduction (last block) --------
__global__ __launch_bounds__(256) void loss_k(
    const float* __restrict__ rowAcc, const float* __restrict__ posv,
    const float* __restrict__ diagE, float* __restrict__ accum,
    unsigned int* __restrict__ cnt, float* __restrict__ out)
{
    const int i = blockIdx.x * 256 + threadIdx.x;
    float s = rowAcc[i] - diagE[i];                 // drop main-diagonal term
    float loss = __logf(s) - posv[i] * 0.0078125f;  // 2*S_pos = acc_pos/128

    #pragma unroll
    for (int m = 1; m < 64; m <<= 1) loss += __shfl_xor(loss, m);
    __shared__ float red[4];
    if ((threadIdx.x & 63) == 0) red[threadIdx.x >> 6] = loss;
    __syncthreads();
    if (threadIdx.x == 0) {
        float bs = red[0] + red[1] + red[2] + red[3];
        atomicAdd(accum, bs);
        __threadfence();
        unsigned int old = atomicAdd(cnt, 1u);
        if (old == 31u) {                       // last of 32 blocks
            __threadfence();
            float total = atomicAdd(accum, 0.0f);
            out[0] = total * (1.0f / (float)N_ROWS);
        }
    }
}

extern "C" void kernel_launch(void* const* d_in, const int* in_sizes, int n_in,
                              void* d_out, int out_size, void* d_ws, size_t ws_size,
                              hipStream_t stream) {
    const float* z_orig = (const float*)d_in[0];
    const float* z_aug  = (const float*)d_in[1];
    char* ws = (char*)d_ws;
    unsigned char* zn   = (unsigned char*)(ws + WS_ZN);
    float* rowAcc       = (float*)(ws + WS_ROWACC);
    float* posv         = (float*)(ws + WS_POS);
    float* diagE        = (float*)(ws + WS_DIAG);
    float* accum        = (float*)(ws + WS_ACC);
    unsigned int* cnt   = (unsigned int*)(ws + WS_CNT);

    normalize_k<<<N_ROWS / 4, 256, 0, stream>>>(z_orig, z_aug, zn, rowAcc, accum, cnt);
    tile_k<<<NUT, 256, 0, stream>>>(zn, rowAcc, posv, diagE);
    loss_k<<<N_ROWS / 256, 256, 0, stream>>>(rowAcc, posv, diagE, accum, cnt,
                                             (float*)d_out);
}

// Round 11
// 92.939 us; speedup vs baseline: 1.9156x; 1.0346x over previous
//
#include <hip/hip_runtime.h>
#include <hip/hip_bf16.h>

typedef __attribute__((ext_vector_type(4))) float f32x4;
typedef __attribute__((ext_vector_type(4))) int   i32x4;
typedef __attribute__((ext_vector_type(8))) int   i32x8;

#define N_ROWS 8192
#define B_HALF 4096
#define NUT   2080          // 64*65/2 upper-triangle 128x128 tiles
// exp(2S) where acc = 256*S (inputs pre-scaled x16): exp2(acc * 2*log2e/256)
#define EXP2C4 0.01127105500694503f
#define SCL1   0x7F7F7F7Fu  // E8M0 127 in all bytes -> scale 1.0

// ws layout (bytes)
#define WS_ZN       0                    // fp4 frag-major [512 groups][2048 B] = 1 MB
#define WS_ROWACC   2097152              // float[8192]  sum_j exp(2 S_ij)
#define WS_POS      2129920              // float[8192]  raw acc_pos (= 256*S_pos)
#define WS_DIAG     2162688              // float[8192]  exp2(acc_ii*EXP2C4)
#define WS_ACC      2195456              // float final accum
#define WS_CNT      2195460              // uint  block counter

__device__ __forceinline__ float fexp2(float x) {
#if __has_builtin(__builtin_amdgcn_exp2f)
    return __builtin_amdgcn_exp2f(x);
#else
    return exp2f(x);
#endif
}

// round-to-nearest e2m1 code (values 0,.5,1,1.5,2,3,4,6), sign in bit 3
__device__ __forceinline__ unsigned int q4(float x) {
    float a = fabsf(x);
    unsigned int s = (__float_as_uint(x) >> 31) << 3;
    unsigned int c = a < 0.25f ? 0u : a < 0.75f ? 1u : a < 1.25f ? 2u
                   : a < 1.75f ? 3u : a < 2.5f  ? 4u : a < 3.5f  ? 5u
                   : a < 5.0f  ? 6u : 7u;
    return c | s;
}

__device__ __forceinline__ i32x8 widen(i32x4 v) {
    return (i32x8){v.x, v.y, v.z, v.w, 0, 0, 0, 0};
}

// 16-lane row sum on the VALU pipe (DPP row_shr), no LDS, no lgkmcnt.
// Result valid in lane 15 of each 16-lane row.
__device__ __forceinline__ float dpp_rowsum16(float x) {
    x += __int_as_float(__builtin_amdgcn_update_dpp(
             0, __float_as_int(x), 0x111, 0xF, 0xF, true));   // row_shr:1
    x += __int_as_float(__builtin_amdgcn_update_dpp(
             0, __float_as_int(x), 0x112, 0xF, 0xF, true));   // row_shr:2
    x += __int_as_float(__builtin_amdgcn_update_dpp(
             0, __float_as_int(x), 0x114, 0xF, 0xF, true));   // row_shr:4
    x += __int_as_float(__builtin_amdgcn_update_dpp(
             0, __float_as_int(x), 0x118, 0xF, 0xF, true));   // row_shr:8
    return x;
}

// ---------------- Phase 1: normalize -> fp4 (x16), FRAGMENT-MAJOR ------------
// (validated R10, absmax 0.0-in-bf16)
__global__ __launch_bounds__(256) void normalize_k(
    const float* __restrict__ z_orig, const float* __restrict__ z_aug,
    unsigned char* __restrict__ zn, float* __restrict__ rowAcc,
    float* __restrict__ accum, unsigned int* __restrict__ cnt)
{
    if (blockIdx.x == 0 && threadIdx.x == 0) { *accum = 0.0f; *cnt = 0u; }
    const int row  = blockIdx.x * 4 + (threadIdx.x >> 6);
    const int lane = threadIdx.x & 63;
    if (lane == 0) rowAcc[row] = 0.0f;       // zeroed before tile_k (stream order)
    const float* src = (row < B_HALF) ? (z_aug  + (size_t)row * 256)
                                      : (z_orig + (size_t)(row - B_HALF) * 256);
    float4 v = ((const float4*)src)[lane];
    float ss = v.x*v.x + v.y*v.y + v.z*v.z + v.w*v.w;
    #pragma unroll
    for (int m = 1; m < 64; m <<= 1) ss += __shfl_xor(ss, m);
    float inv = 16.0f / fmaxf(sqrtf(ss), 1e-8f);   // x16 pre-scale into e2m1 range
    unsigned int pk = q4(v.x * inv) | (q4(v.y * inv) << 4)
                    | (q4(v.z * inv) << 8) | (q4(v.w * inv) << 12);
    const int addr = ((row >> 4) << 11) | ((lane >> 5) << 10) | ((row & 15) << 6)
                   | (((lane >> 3) & 3) << 4) | ((lane & 7) << 1);
    *(unsigned short*)(zn + addr) = (unsigned short)pk;
}

// ---------------- Phase 2: LDS-free fp4 128x128 tiles, DPP epilogue ----------
__global__ __launch_bounds__(256, 3) void tile_k(
    const unsigned char* __restrict__ zn,
    float* __restrict__ rowAcc,         // [8192] += sum_j exp(2 S_ij)
    float* __restrict__ posv,           // [8192] raw acc_pos
    float* __restrict__ diagE)          // [8192] exp2(acc_ii*EXP2C4)
{
    const int bid = blockIdx.x;
    // decode upper-triangular (rb, cb), cb >= rb; C(r) = r*(129-r)/2
    int rb = (int)((129.0f - sqrtf(16641.0f - 8.0f * (float)bid)) * 0.5f);
    rb = rb < 0 ? 0 : (rb > 63 ? 63 : rb);
    while ((rb + 1) * (129 - (rb + 1)) / 2 <= bid) ++rb;
    while (rb * (129 - rb) / 2 > bid) --rb;
    const int cb = rb + (bid - rb * (129 - rb) / 2);

    const int t      = threadIdx.x;
    const int lane   = t & 63;
    const int w      = t >> 6;
    const int wy     = w >> 1;
    const int wx     = w & 1;
    const int lane15 = lane & 15;
    const int quad   = lane >> 4;
    const int rowBase = rb * 128;
    const int colBase = cb * 128;

    const int laneOff = lane15 * 64 + quad * 16;
    const unsigned char* gA = zn + (size_t)(rb * 8 + wy * 4) * 2048 + laneOff;
    const unsigned char* gB = zn + (size_t)(cb * 8 + wx * 4) * 2048 + laneOff;

    f32x4 acc[4][4];
    #pragma unroll
    for (int i = 0; i < 4; ++i)
        #pragma unroll
        for (int j = 0; j < 4; ++j)
            acc[i][j] = (f32x4){0.f, 0.f, 0.f, 0.f};

    #pragma unroll                           // FULL unroll: all loads up front
    for (int ks = 0; ks < 2; ++ks) {
        i32x4 a[4], b[4];
        #pragma unroll
        for (int mi = 0; mi < 4; ++mi)
            a[mi] = *(const i32x4*)(gA + mi * 2048 + ks * 1024);
        #pragma unroll
        for (int ni = 0; ni < 4; ++ni)
            b[ni] = *(const i32x4*)(gB + ni * 2048 + ks * 1024);
        #pragma unroll
        for (int mi = 0; mi < 4; ++mi)
            #pragma unroll
            for (int ni = 0; ni < 4; ++ni)
                acc[mi][ni] = __builtin_amdgcn_mfma_scale_f32_16x16x128_f8f6f4(
                    widen(a[mi]), widen(b[ni]), acc[mi][ni],
                    4, 4,                     // cbsz=4 (fp4 A), blgp=4 (fp4 B)
                    0, SCL1, 0, SCL1);
    }

    // C/D layout: m-row = quad*4 + reg, n-col = lane15 (validated r1-r10).
    const bool diagLane = (wy == wx) && ((lane15 >> 2) == quad);
    const int  rsel = lane15 & 3;
    if (cb == rb && diagLane) {
        #pragma unroll
        for (int mi = 0; mi < 4; ++mi) {
            int grow = rowBase + wy * 64 + mi * 16 + lane15;
            diagE[grow] = fexp2(acc[mi][mi][rsel] * EXP2C4);
        }
    }
    if (cb == rb + 32 && diagLane) {         // positive-pair diagonal
        #pragma unroll
        for (int mi = 0; mi < 4; ++mi) {
            int grow = rowBase + wy * 64 + mi * 16 + lane15;
            float v = acc[mi][mi][rsel];
            posv[grow] = v;
            posv[grow + B_HALF] = v;
        }
    }

    // exp(2*S) in place (acc = 256*S)
    #pragma unroll
    for (int mi = 0; mi < 4; ++mi)
        #pragma unroll
        for (int ni = 0; ni < 4; ++ni)
            #pragma unroll
            for (int r = 0; r < 4; ++r)
                acc[mi][ni][r] = fexp2(acc[mi][ni][r] * EXP2C4);

    // row sums (over n): DPP 16-lane reduce on VALU pipe; atomic from lane 15
    #pragma unroll
    for (int mi = 0; mi < 4; ++mi)
        #pragma unroll
        for (int r = 0; r < 4; ++r) {
            float s = acc[mi][0][r] + acc[mi][1][r] + acc[mi][2][r] + acc[mi][3][r];
            s = dpp_rowsum16(s);
            if (lane15 == 15)
                atomicAdd(&rowAcc[rowBase + wy * 64 + mi * 16 + quad * 4 + r], s);
        }

    // col sums (over m = quad rows); cross-row -> keep 2 shuffles; off-diag only
    if (cb != rb) {
        #pragma unroll
        for (int ni = 0; ni < 4; ++ni) {
            float s = 0.0f;
            #pragma unroll
            for (int mi = 0; mi < 4; ++mi)
                s += acc[mi][ni][0] + acc[mi][ni][1] + acc[mi][ni][2] + acc[mi][ni][3];
            s += __shfl_xor(s, 16);
            s += __shfl_xor(s, 32);
            if (quad == 0)
                atomicAdd(&rowAcc[colBase + wx * 64 + ni * 16 + lane15], s);
        }
    }
}

// ---------------- Phase 3: per-row loss + grid reduction (last block) --------
__global__ __launch_bounds__(256) void loss_k(
    const float* __restrict__ rowAcc, const float* __restrict__ posv,
    const float* __restrict__ diagE, float* __restrict__ accum,
    unsigned int* __restrict__ cnt, float* __restrict__ out)
{
    const int i = blockIdx.x * 256 + threadIdx.x;
    float s = rowAcc[i] - diagE[i];                 // drop main-diagonal term
    float loss = __logf(s) - posv[i] * 0.0078125f;  // 2*S_pos = acc_pos/128

    #pragma unroll
    for (int m = 1; m < 64; m <<= 1) loss += __shfl_xor(loss, m);
    __shared__ float red[4];
    if ((threadIdx.x & 63) == 0) red[threadIdx.x >> 6] = loss;
    __syncthreads();
    if (threadIdx.x == 0) {
        float bs = red[0] + red[1] + red[2] + red[3];
        atomicAdd(accum, bs);
        __threadfence();
        unsigned int old = atomicAdd(cnt, 1u);
        if (old == 31u) {                       // last of 32 blocks
            __threadfence();
            float total = atomicAdd(accum, 0.0f);
            out[0] = total * (1.0f / (float)N_ROWS);
        }
    }
}

extern "C" void kernel_launch(void* const* d_in, const int* in_sizes, int n_in,
                              void* d_out, int out_size, void* d_ws, size_t ws_size,
                              hipStream_t stream) {
    const float* z_orig = (const float*)d_in[0];
    const float* z_aug  = (const float*)d_in[1];
    char* ws = (char*)d_ws;
    unsigned char* zn   = (unsigned char*)(ws + WS_ZN);
    float* rowAcc       = (float*)(ws + WS_ROWACC);
    float* posv         = (float*)(ws + WS_POS);
    float* diagE        = (float*)(ws + WS_DIAG);
    float* accum        = (float*)(ws + WS_ACC);
    unsigned int* cnt   = (unsigned int*)(ws + WS_CNT);

    normalize_k<<<N_ROWS / 4, 256, 0, stream>>>(z_orig, z_aug, zn, rowAcc, accum, cnt);
    tile_k<<<NUT, 256, 0, stream>>>(zn, rowAcc, posv, diagE);
    loss_k<<<N_ROWS / 256, 256, 0, stream>>>(rowAcc, posv, diagE, accum, cnt,
                                             (float*)d_out);
}